// Round 8
// baseline (263.079 us; speedup 1.0000x reference)
//
#include <hip/hip_runtime.h>
#include <hip/hip_bf16.h>
#include <math.h>

#define D_MODEL 1024
#define NHEADS  16
#define HDIM    64
#define BATCH   4
#define SLEN    2048
#define MROWS   (BATCH * SLEN)        // 8192
#define QKV_N   (3 * D_MODEL)         // 3072

typedef __attribute__((ext_vector_type(8))) short bhalf8;   // 8 bf16 = 4 VGPRs (MFMA A/B frag)
typedef __attribute__((ext_vector_type(4))) float f32x4;    // MFMA C/D frag

#if __has_builtin(__builtin_amdgcn_exp2f)
#define EXP2(x) __builtin_amdgcn_exp2f(x)       // raw v_exp_f32, 1 instr
#else
#define EXP2(x) exp2f(x)
#endif

#define MFMA16(a, b, c) __builtin_amdgcn_mfma_f32_16x16x32_bf16((a), (b), (c), 0, 0, 0)

static __device__ __forceinline__ unsigned short f2bf(float f) {
    unsigned int u = __builtin_bit_cast(unsigned int, f);
    unsigned int r = (u + 0x7FFFu + ((u >> 16) & 1u)) >> 16;   // RNE
    return (unsigned short)r;
}

// pack hi16(lo), hi16(hi) -> one dword (bf16 truncation) via v_perm_b32
static __device__ __forceinline__ unsigned int pack_hi16(float lo, float hi) {
    return __builtin_amdgcn_perm(__builtin_bit_cast(unsigned int, hi),
                                 __builtin_bit_cast(unsigned int, lo),
                                 0x07060302u);
}

// async 16B global -> LDS (emits global_load_lds_dwordx4). LDS dest must be
// wave-uniform base + lane*16 (m104/m108) — all call sites obey this.
static __device__ __forceinline__ void load_lds16(const void* g, void* l) {
    __builtin_amdgcn_global_load_lds(
        (const __attribute__((address_space(1))) void*)g,
        (__attribute__((address_space(3))) void*)l, 16, 0, 0);
}

// compiler-level memory fence + raw barrier (no vmcnt(0) drain, unlike __syncthreads)
#define FENCE() __asm__ volatile("" ::: "memory")
#define BARRIER() do { FENCE();                                   \
        __builtin_amdgcn_sched_barrier(0);                        \
        __builtin_amdgcn_s_barrier();                             \
        __builtin_amdgcn_sched_barrier(0); FENCE(); } while (0)
#define WAIT_VM(N)   __asm__ volatile("s_waitcnt vmcnt(" #N ")" ::: "memory")
#define WAIT_LGKM0() __asm__ volatile("s_waitcnt lgkmcnt(0)" ::: "memory")

// ---------------------------------------------------------------------------
// fused fp32 -> bf16 cast over three regions (x, qkv_w, out_w) in ONE dispatch.
// ---------------------------------------------------------------------------
__global__ __launch_bounds__(256) void cast3_f32_bf16(
    const float* __restrict__ a, unsigned short* __restrict__ oa, int na,
    const float* __restrict__ b, unsigned short* __restrict__ ob, int nb,
    const float* __restrict__ c, unsigned short* __restrict__ oc, int nc)
{
    int i = (blockIdx.x * 256 + threadIdx.x) * 4;
    const float* src;
    unsigned short* dst;
    if (i < na)           { src = a + i;            dst = oa + i; }
    else if (i < na + nb) { src = b + (i - na);     dst = ob + (i - na); }
    else {
        int j = i - na - nb;
        if (j >= nc) return;
        src = c + j; dst = oc + j;
    }
    float4 v = *(const float4*)src;
    ushort4 o;
    o.x = f2bf(v.x); o.y = f2bf(v.y); o.z = f2bf(v.z); o.w = f2bf(v.w);
    *(ushort4*)dst = o;
}

// ---------------------------------------------------------------------------
// MFMA GEMM (Linear semantics): out[m][n] = (sum_k A[m][k]*W[n][k] + bias[n])
//                                           * (n < qcols ? qscale : 1)
// 128x128 tile, BK=32, 256 thr, RING-3 LDS (48 KB, 3 blocks/CU unchanged),
// distance-2 prefetch, counted vmcnt(4) — ZERO vmcnt(0) drains in steady
// state (round 7 proved drain count is the binding stall: halving it won
// 11 µs; this removes the rest). One raw barrier per K-tile.
// Ledger: WAR — stage(t+2) targets slot (t-1)%3 whose last readers' ds_reads
// completed before the end-of-tile-(t-1) barrier. RAW — slot t%3 staged at
// t-2, landed by the vmcnt(4) at end of t-1 (oldest 4 = that stage) +
// barrier for cross-wave visibility. Requires (K/32) % 3 == 2 (K=1024: ✓).
// Staging/read swizzle and K-accumulation order identical to the round-0
// proven kernel. XCD-bijective block swizzle kept.
// ---------------------------------------------------------------------------
template<bool BF16OUT>
__global__ __launch_bounds__(256) void gemm_mfma_bt(
    const unsigned short* __restrict__ A,
    const unsigned short* __restrict__ W,
    const float* __restrict__ bias,
    void* __restrict__ outv,
    int M, int N, int K, int qcols, float qscale)
{
    __shared__ __align__(16) unsigned short As[3][128 * 32];   // 24 KB
    __shared__ __align__(16) unsigned short Bs[3][128 * 32];   // 24 KB

    // XCD-bijective swizzle (requires nwg % 8 == 0; both our grids qualify)
    int bxs = blockIdx.x, bys = blockIdx.y;
    {
        const int nx  = gridDim.x;
        const int nwg = nx * gridDim.y;
        if ((nwg & 7) == 0) {
            const int orig = bys * nx + bxs;
            const int nf   = (orig & 7) * (nwg >> 3) + (orig >> 3);
            bxs = nf % nx;
            bys = nf / nx;
        }
    }

    const int tid  = threadIdx.x;
    const int bm   = bys * 128;
    const int bn   = bxs * 128;
    const int wave = tid >> 6;
    const int lane = tid & 63;
    const int m16  = lane & 15;
    const int quad = lane >> 4;
    const int wm   = (wave & 1) * 64;
    const int wn   = (wave >> 1) * 64;

    const int r0 = tid >> 2;
    const int s0 = tid & 3;
    const int g0 = (s0 - (r0 >> 1)) & 3;
    const int g1 = (s0 - ((r0 + 64) >> 1)) & 3;

    const size_t arow0 = (size_t)(bm + r0) * K + g0 * 8;
    const size_t arow1 = (size_t)(bm + r0 + 64) * K + g1 * 8;
    const size_t brow0 = (size_t)(bn + r0) * K + g0 * 8;
    const size_t brow1 = (size_t)(bn + r0 + 64) * K + g1 * 8;

    f32x4 acc[4][4];
    f32x4 zero = {0.f, 0.f, 0.f, 0.f};
#pragma unroll
    for (int i = 0; i < 4; ++i)
#pragma unroll
        for (int j = 0; j < 4; ++j) acc[i][j] = zero;

    // 4 loads/thread per stage -> vmcnt counts: 2 stages in flight = 8.
#define G_STAGE(T, SLOT) do {                                        \
        const int ko_ = (T) << 5;                                    \
        load_lds16(A + arow0 + ko_, As[SLOT] + tid * 8);             \
        load_lds16(A + arow1 + ko_, As[SLOT] + 2048 + tid * 8);      \
        load_lds16(W + brow0 + ko_, Bs[SLOT] + tid * 8);             \
        load_lds16(W + brow1 + ko_, Bs[SLOT] + 2048 + tid * 8);      \
    } while (0)

#define G_COMPUTE(CUR) do {                                          \
        bhalf8 af[4], bf[4];                                         \
        _Pragma("unroll")                                            \
        for (int i = 0; i < 4; ++i) {                                \
            int ra = wm + i * 16 + m16;                              \
            int sa = (quad + (ra >> 1)) & 3;                         \
            af[i] = *(const bhalf8*)&As[CUR][ra * 32 + sa * 8];      \
        }                                                            \
        _Pragma("unroll")                                            \
        for (int j = 0; j < 4; ++j) {                                \
            int rb = wn + j * 16 + m16;                              \
            int sb = (quad + (rb >> 1)) & 3;                         \
            bf[j] = *(const bhalf8*)&Bs[CUR][rb * 32 + sb * 8];      \
        }                                                            \
        __builtin_amdgcn_s_setprio(1);                               \
        _Pragma("unroll")                                            \
        for (int i = 0; i < 4; ++i)                                  \
            _Pragma("unroll")                                        \
            for (int j = 0; j < 4; ++j)                              \
                acc[i][j] = MFMA16(af[i], bf[j], acc[i][j]);         \
        __builtin_amdgcn_s_setprio(0);                               \
    } while (0)

    // prologue: tiles 0,1 staged into slots 0,1; wait tile 0 only
    G_STAGE(0, 0);
    G_STAGE(1, 1);
    WAIT_VM(4);                 // tile 0 landed; tile 1 in flight
    BARRIER();

    // main loop: tiles 0..NT-3 each stage tile t+2 into slot (t+2)%3.
    // (NT-2) % 3 == 0 required (NT=32 here -> 30 = 10x3).
    const int NT = K >> 5;
    for (int t3 = 0; t3 < NT - 2; t3 += 3) {
        G_STAGE(t3 + 2, 2); G_COMPUTE(0); WAIT_VM(4); BARRIER();
        G_STAGE(t3 + 3, 0); G_COMPUTE(1); WAIT_VM(4); BARRIER();
        G_STAGE(t3 + 4, 1); G_COMPUTE(2); WAIT_VM(4); BARRIER();
    }

    // tile NT-2 (slot 0): no stage; only tile NT-1's 4 loads remain
    G_COMPUTE(0);
    WAIT_VM(0);
    BARRIER();
    // tile NT-1 (slot 1): compute only
    G_COMPUTE(1);

#undef G_COMPUTE
#undef G_STAGE

    float bj[4], scj[4];
#pragma unroll
    for (int j = 0; j < 4; ++j) {
        int col = bn + wn + j * 16 + m16;
        bj[j]  = bias[col];
        scj[j] = (col < qcols) ? qscale : 1.0f;
    }

#pragma unroll
    for (int i = 0; i < 4; ++i) {
#pragma unroll
        for (int r = 0; r < 4; ++r) {
            size_t row = (size_t)(bm + wm + i * 16 + quad * 4 + r);
            if (BF16OUT) {
                unsigned short* dst = (unsigned short*)outv + row * N + bn + wn;
#pragma unroll
                for (int j = 0; j < 4; ++j)
                    dst[j * 16 + m16] = f2bf((acc[i][j][r] + bj[j]) * scj[j]);
            } else {
                float* dst = (float*)outv + row * N + bn + wn;
#pragma unroll
                for (int j = 0; j < 4; ++j)
                    dst[j * 16 + m16] = (acc[i][j][r] + bj[j]) * scj[j];
            }
        }
    }
}

// ---------------------------------------------------------------------------
// MFMA flash attention — ROUND-2/6 KERNEL, FROZEN (measured 87.5/88.5 µs,
// best of all rounds). 128 q-rows/block, 4 waves x 32 rows, 3-barrier
// counted-vmcnt pipeline, XCD-bijective swizzle (FETCH 139->26 MB).
// Rounds 3/4/5 established: 1-barrier dbuf (-), 8-wave blocks (spill, -),
// QBLK=64 high-occupancy (-). Grid-capped at 16 waves/CU; local optimum.
// ---------------------------------------------------------------------------
__global__ __launch_bounds__(256, 4) void attn_mfma_kernel(
    const unsigned short* __restrict__ qkv, unsigned short* __restrict__ ctx)
{
    // bijective XCD swizzle: 1024 blocks = 8 * 128 exactly
    const int orig = blockIdx.x + (blockIdx.y << 4) + (blockIdx.z << 8);
    const int flat = ((orig & 7) << 7) | (orig >> 3);
    const int qt = flat & 15;            // 0..15 (128-row q tiles)
    const int h  = (flat >> 4) & 15;     // 0..15
    const int b  = flat >> 8;            // 0..3

    const int tid  = threadIdx.x;
    const int wave = tid >> 6;
    const int lane = tid & 63;
    const int m16  = lane & 15;
    const int quad = lane >> 4;

    __shared__ __align__(16) unsigned short K_lds[64 * 64];        // 8 KB
    __shared__ __align__(16) unsigned short Vt_lds[64 * 72];       // 9 KB
    __shared__ __align__(16) unsigned short QP_lds[4 * 32 * 72];   // 18 KB: Q stage, then P

    const int srow  = tid >> 3;          // 0..31 per 32-row staging chunk
    const int sslot = tid & 7;
    const int gk    = (sslot - srow) & 7;   // same rotation for both 32-row halves

    // V staging assignment: thread u handles key pair (k0, k0+16) -> storage
    // idx0, idx0+1 (adjacent); 8 d-rows starting vd0.
    const int u    = tid & 31;
    const int k0   = (u & 15) | ((u & 16) << 1);
    const int idx0 = (u & 15) * 4 + ((u >> 4) << 1);
    const int vd0  = (tid >> 5) * 8;

    const unsigned short* kPtr =
        qkv + ((size_t)b * SLEN) * QKV_N + D_MODEL + h * HDIM
            + (size_t)srow * QKV_N + gk * 8;
    const unsigned short* vPtr0 =
        qkv + ((size_t)b * SLEN) * QKV_N + 2 * D_MODEL + h * HDIM
            + (size_t)k0 * QKV_N + vd0;
    const unsigned short* vPtr1 = vPtr0 + (size_t)16 * QKV_N;

    uint4 va_A, vb_A, va_B, vb_B;

#define ISSUE_K(T) do {                                                      \
        const unsigned short* kb_ = kPtr + (size_t)(T) * 64 * QKV_N;         \
        load_lds16(kb_,                        K_lds + tid * 8);             \
        load_lds16(kb_ + (size_t)32 * QKV_N,   K_lds + 2048 + tid * 8);      \
    } while (0)

#define ISSUE_V(T, VA, VB) do {                                              \
        VA = *(const uint4*)(vPtr0 + (size_t)(T) * 64 * QKV_N);              \
        VB = *(const uint4*)(vPtr1 + (size_t)(T) * 64 * QKV_N);              \
    } while (0)

#define WRITE_V(VA, VB) do {                                                                         \
        *(unsigned int*)&Vt_lds[(vd0 + 0) * 72 + idx0] = __builtin_amdgcn_perm(VB.x, VA.x, 0x05040100u); \
        *(unsigned int*)&Vt_lds[(vd0 + 1) * 72 + idx0] = __builtin_amdgcn_perm(VB.x, VA.x, 0x07060302u); \
        *(unsigned int*)&Vt_lds[(vd0 + 2) * 72 + idx0] = __builtin_amdgcn_perm(VB.y, VA.y, 0x05040100u); \
        *(unsigned int*)&Vt_lds[(vd0 + 3) * 72 + idx0] = __builtin_amdgcn_perm(VB.y, VA.y, 0x07060302u); \
        *(unsigned int*)&Vt_lds[(vd0 + 4) * 72 + idx0] = __builtin_amdgcn_perm(VB.z, VA.z, 0x05040100u); \
        *(unsigned int*)&Vt_lds[(vd0 + 5) * 72 + idx0] = __builtin_amdgcn_perm(VB.z, VA.z, 0x07060302u); \
        *(unsigned int*)&Vt_lds[(vd0 + 6) * 72 + idx0] = __builtin_amdgcn_perm(VB.w, VA.w, 0x05040100u); \
        *(unsigned int*)&Vt_lds[(vd0 + 7) * 72 + idx0] = __builtin_amdgcn_perm(VB.w, VA.w, 0x07060302u); \
    } while (0)

    // ---- prologue: stage Q (4 ops), K(0) (2 ops), V(0) regs (2 ops) ----
    {
        const unsigned short* qbase =
            qkv + (size_t)(b * SLEN + qt * 128) * QKV_N + h * HDIM;
#pragma unroll
        for (int c = 0; c < 4; ++c) {
            int r = c * 32 + srow;
            int g = (sslot - r) & 7;
            load_lds16(qbase + (size_t)r * QKV_N + g * 8,
                       QP_lds + c * 2048 + tid * 8);
        }
    }
    ISSUE_K(0);
    ISSUE_V(0, va_A, vb_A);
    WAIT_VM(2);            // Q(4)+K0(2) landed; V0 regs still in flight
    BARRIER();

    // ---- hoist Q frags (loop-invariant); QP region becomes P afterwards ----
    bhalf8 qf[2][2];
#pragma unroll
    for (int qi = 0; qi < 2; ++qi) {
        int rq = wave * 32 + qi * 16 + m16;
#pragma unroll
        for (int ks = 0; ks < 2; ++ks) {
            int slot = (ks * 4 + quad + rq) & 7;
            qf[qi][ks] = *(const bhalf8*)&QP_lds[rq * 64 + slot * 8];
        }
    }

    WAIT_VM(0);                 // V(0) regs landed
    WRITE_V(va_A, vb_A);        // V(0) -> Vt_lds
    ISSUE_V(1, va_B, vb_B);     // V(1) regs in flight (2 ops)
    WAIT_LGKM0();
    BARRIER();
    // loop-entry invariant at t: K_lds=K(t) ready, Vt_lds=V(t) ready,
    // V(t+1) regs in flight, K(t+1) not yet issued.

    f32x4 zero = {0.f, 0.f, 0.f, 0.f};
    f32x4 oacc[2][4], oacc_l[2];
#pragma unroll
    for (int qi = 0; qi < 2; ++qi) {
        oacc_l[qi] = zero;
#pragma unroll
        for (int dt = 0; dt < 4; ++dt) oacc[qi][dt] = zero;
    }

    bhalf8 ones;
#pragma unroll
    for (int i = 0; i < 8; ++i) ones[i] = (short)0x3F80;   // bf16 1.0

    unsigned short* P = &QP_lds[wave * (32 * 72)];
    f32x4 sacc[2][4];

#define QKT_PHASE() do {                                                     \
        _Pragma("unroll")                                                    \
        for (int qi = 0; qi < 2; ++qi)                                       \
            _Pragma("unroll")                                                \
            for (int nt = 0; nt < 4; ++nt) sacc[qi][nt] = zero;              \
        __builtin_amdgcn_s_setprio(1);                                       \
        _Pragma("unroll")                                                    \
        for (int ks = 0; ks < 2; ++ks) {                                     \
            _Pragma("unroll")                                                \
            for (int nt = 0; nt < 4; ++nt) {                                 \
                int rk = nt * 16 + m16;                                      \
                int slot = (ks * 4 + quad + rk) & 7;                         \
                bhalf8 kf = *(const bhalf8*)&K_lds[rk * 64 + slot * 8];      \
                sacc[0][nt] = MFMA16(qf[0][ks], kf, sacc[0][nt]);            \
                sacc[1][nt] = MFMA16(qf[1][ks], kf, sacc[1][nt]);            \
            }                                                                \
        }                                                                    \
        __builtin_amdgcn_s_setprio(0);                                       \
    } while (0)

#define SOFTMAX_PHASE() do {                                                 \
        _Pragma("unroll")                                                    \
        for (int qi = 0; qi < 2; ++qi) {                                     \
            _Pragma("unroll")                                                \
            for (int r = 0; r < 4; ++r) {                                    \
                float p0 = EXP2(sacc[qi][0][r]);                             \
                float p1 = EXP2(sacc[qi][1][r]);                             \
                float p2 = EXP2(sacc[qi][2][r]);                             \
                float p3 = EXP2(sacc[qi][3][r]);                             \
                uint2 w;                                                     \
                w.x = pack_hi16(p0, p1);                                     \
                w.y = pack_hi16(p2, p3);                                     \
                *(uint2*)&P[(qi * 16 + quad * 4 + r) * 72 + m16 * 4] = w;    \
            }                                                                \
        }                                                                    \
        WAIT_LGKM0();                                                        \
        __builtin_amdgcn_sched_barrier(0);                                   \
    } while (0)

#define PV_PHASE() do {                                                      \
        __builtin_amdgcn_s_setprio(1);                                       \
        _Pragma("unroll")                                                    \
        for (int ks = 0; ks < 2; ++ks) {                                     \
            bhalf8 pf0 = *(const bhalf8*)&P[(m16)      * 72 + ks * 32 + quad * 8]; \
            bhalf8 pf1 = *(const bhalf8*)&P[(16 + m16) * 72 + ks * 32 + quad * 8]; \
            oacc_l[0] = MFMA16(pf0, ones, oacc_l[0]);                        \
            oacc_l[1] = MFMA16(pf1, ones, oacc_l[1]);                        \
            _Pragma("unroll")                                                \
            for (int dt = 0; dt < 4; ++dt) {                                 \
                bhalf8 vf = *(const bhalf8*)&Vt_lds[(dt * 16 + m16) * 72 + ks * 32 + quad * 8]; \
                oacc[0][dt] = MFMA16(pf0, vf, oacc[0][dt]);                  \
                oacc[1][dt] = MFMA16(pf1, vf, oacc[1][dt]);                  \
            }                                                                \
        }                                                                    \
        __builtin_amdgcn_s_setprio(0);                                       \
    } while (0)

// full-pipeline tile: issue K(T+1), write V(T+1), issue V(T+2)
#define TILE_FULL(T, VWA, VWB, VLA, VLB) do {                                \
        QKT_PHASE();                                                         \
        BARRIER();                    /* B1: all waves done reading K_lds */ \
        ISSUE_K((T) + 1);                                                    \
        SOFTMAX_PHASE();                                                     \
        PV_PHASE();                                                          \
        BARRIER();                    /* B2: all waves done reading Vt/P  */ \
        WAIT_VM(2);                   /* V(T+1) regs landed; K(T+1) fly  */  \
        WRITE_V(VWA, VWB);                                                   \
        ISSUE_V((T) + 2, VLA, VLB);                                          \
        WAIT_VM(2);                   /* K(T+1) landed; V(T+2) in flight */  \
        WAIT_LGKM0();                                                        \
        BARRIER();                    /* B3: K(T+1)/Vt(T+1) visible */       \
    } while (0)

    // main loop: tiles 0..29, x2 unroll for static V-reg set parity
    for (int t2 = 0; t2 < 30; t2 += 2) {
        TILE_FULL(t2,     va_B, vb_B, va_A, vb_A);
        TILE_FULL(t2 + 1, va_A, vb_A, va_B, vb_B);
    }

    // t = 30: issue K(31), write V(31) (setB), no V(32)
    QKT_PHASE();
    BARRIER();
    ISSUE_K(31);
    SOFTMAX_PHASE();
    PV_PHASE();
    BARRIER();
    WAIT_VM(2);                 // V(31) regs landed
    WRITE_V(va_B, vb_B);
    WAIT_VM(0);                 // K(31) landed
    WAIT_LGKM0();
    BARRIER();

    // t = 31: pure compute
    QKT_PHASE();
    SOFTMAX_PHASE();
    PV_PHASE();

#undef TILE_FULL
#undef PV_PHASE
#undef SOFTMAX_PHASE
#undef QKT_PHASE
#undef WRITE_V
#undef ISSUE_V
#undef ISSUE_K

    // ---- epilogue: l is per-lane in C-layout (same col value across cols) ----
#pragma unroll
    for (int qi = 0; qi < 2; ++qi) {
#pragma unroll
        for (int r = 0; r < 4; ++r) {
            float inv = 1.0f / oacc_l[qi][r];
            int row = b * SLEN + qt * 128 + wave * 32 + qi * 16 + quad * 4 + r;
            unsigned short* dst = ctx + (size_t)row * D_MODEL + h * HDIM;
#pragma unroll
            for (int dt = 0; dt < 4; ++dt)
                dst[dt * 16 + m16] = f2bf(oacc[qi][dt][r] * inv);
        }
    }
}

// ---------------------------------------------------------------------------
extern "C" void kernel_launch(void* const* d_in, const int* in_sizes, int n_in,
                              void* d_out, int out_size, void* d_ws, size_t ws_size,
                              hipStream_t stream)
{
    const float* x     = (const float*)d_in[0];   // [4,2048,1024]
    const float* qkv_w = (const float*)d_in[1];   // [3072,1024]
    const float* qkv_b = (const float*)d_in[2];   // [3072]
    const float* out_w = (const float*)d_in[3];   // [1024,1024]
    const float* out_b = (const float*)d_in[4];   // [1024]
    float* out = (float*)d_out;                   // [4,2048,1024]

    unsigned short* xbf  = (unsigned short*)d_ws;                 // [8192,1024]
    unsigned short* wqkv = xbf  + (size_t)MROWS * D_MODEL;        // [3072,1024]
    unsigned short* wout = wqkv + (size_t)QKV_N * D_MODEL;        // [1024,1024]
    unsigned short* qkv  = wout + (size_t)D_MODEL * D_MODEL;      // [8192,3072]
    unsigned short* ctx  = qkv  + (size_t)MROWS * QKV_N;          // [8192,1024]

    // 0) fused fp32 -> bf16 casts (one dispatch)
    {
        const int na = MROWS * D_MODEL;      // 8388608
        const int nb = QKV_N * D_MODEL;      // 3145728
        const int nc = D_MODEL * D_MODEL;    // 1048576
        const int total = na + nb + nc;      // 12582912, /1024 = 12288
        cast3_f32_bf16<<<total / 1024, 256, 0, stream>>>(
            x, xbf, na, qkv_w, wqkv, nb, out_w, wout, nc);
    }

    const float QSCALE = 0.125f * 1.44269504088896f;   // 1/sqrt(64) * log2(e)

    // 1) QKV projection (ring-3); q columns (<1024) pre-scaled for exp2 softmax
    {
        dim3 grid(QKV_N / 128, MROWS / 128);   // 24 x 64 = 1536 blocks (%8==0)
        gemm_mfma_bt<true><<<grid, 256, 0, stream>>>(xbf, wqkv, qkv_b, qkv,
                                                     MROWS, QKV_N, D_MODEL,
                                                     D_MODEL, QSCALE);
    }

    // 2) round-2 pipelined MFMA flash attention -> bf16 ctx (frozen)
    {
        dim3 grid(SLEN / 128, NHEADS, BATCH);
        attn_mfma_kernel<<<grid, 256, 0, stream>>>(qkv, ctx);
    }

    // 3) output projection (ring-3) -> fp32 d_out
    {
        dim3 grid(D_MODEL / 128, MROWS / 128); // 8 x 64 = 512 blocks (%8==0)
        gemm_mfma_bt<false><<<grid, 256, 0, stream>>>(ctx, wout, out_b, out,
                                                      MROWS, D_MODEL, D_MODEL,
                                                      0, 1.0f);
    }
}

// Round 9
// 251.372 us; speedup vs baseline: 1.0466x; 1.0466x over previous
//
#include <hip/hip_runtime.h>
#include <hip/hip_bf16.h>
#include <math.h>

#define D_MODEL 1024
#define NHEADS  16
#define HDIM    64
#define BATCH   4
#define SLEN    2048
#define MROWS   (BATCH * SLEN)        // 8192
#define QKV_N   (3 * D_MODEL)         // 3072

typedef __attribute__((ext_vector_type(8))) short bhalf8;   // 8 bf16 = 4 VGPRs (MFMA A/B frag)
typedef __attribute__((ext_vector_type(4))) float f32x4;    // MFMA C/D frag

#if __has_builtin(__builtin_amdgcn_exp2f)
#define EXP2(x) __builtin_amdgcn_exp2f(x)       // raw v_exp_f32, 1 instr
#else
#define EXP2(x) exp2f(x)
#endif

#define MFMA16(a, b, c) __builtin_amdgcn_mfma_f32_16x16x32_bf16((a), (b), (c), 0, 0, 0)

static __device__ __forceinline__ unsigned short f2bf(float f) {
    unsigned int u = __builtin_bit_cast(unsigned int, f);
    unsigned int r = (u + 0x7FFFu + ((u >> 16) & 1u)) >> 16;   // RNE
    return (unsigned short)r;
}

// pack hi16(lo), hi16(hi) -> one dword (bf16 truncation) via v_perm_b32
static __device__ __forceinline__ unsigned int pack_hi16(float lo, float hi) {
    return __builtin_amdgcn_perm(__builtin_bit_cast(unsigned int, hi),
                                 __builtin_bit_cast(unsigned int, lo),
                                 0x07060302u);
}

// async 16B global -> LDS (emits global_load_lds_dwordx4). LDS dest must be
// wave-uniform base + lane*16 (m104/m108) — all call sites obey this.
static __device__ __forceinline__ void load_lds16(const void* g, void* l) {
    __builtin_amdgcn_global_load_lds(
        (const __attribute__((address_space(1))) void*)g,
        (__attribute__((address_space(3))) void*)l, 16, 0, 0);
}

// compiler-level memory fence + raw barrier (no vmcnt(0) drain, unlike __syncthreads)
#define FENCE() __asm__ volatile("" ::: "memory")
#define BARRIER() do { FENCE();                                   \
        __builtin_amdgcn_sched_barrier(0);                        \
        __builtin_amdgcn_s_barrier();                             \
        __builtin_amdgcn_sched_barrier(0); FENCE(); } while (0)
#define WAIT_VM(N)   __asm__ volatile("s_waitcnt vmcnt(" #N ")" ::: "memory")
#define WAIT_LGKM0() __asm__ volatile("s_waitcnt lgkmcnt(0)" ::: "memory")

// ---------------------------------------------------------------------------
// fused fp32 -> bf16 cast over three regions (x, qkv_w, out_w) in ONE dispatch.
// ---------------------------------------------------------------------------
__global__ __launch_bounds__(256) void cast3_f32_bf16(
    const float* __restrict__ a, unsigned short* __restrict__ oa, int na,
    const float* __restrict__ b, unsigned short* __restrict__ ob, int nb,
    const float* __restrict__ c, unsigned short* __restrict__ oc, int nc)
{
    int i = (blockIdx.x * 256 + threadIdx.x) * 4;
    const float* src;
    unsigned short* dst;
    if (i < na)           { src = a + i;            dst = oa + i; }
    else if (i < na + nb) { src = b + (i - na);     dst = ob + (i - na); }
    else {
        int j = i - na - nb;
        if (j >= nc) return;
        src = c + j; dst = oc + j;
    }
    float4 v = *(const float4*)src;
    ushort4 o;
    o.x = f2bf(v.x); o.y = f2bf(v.y); o.z = f2bf(v.z); o.w = f2bf(v.w);
    *(ushort4*)dst = o;
}

// ---------------------------------------------------------------------------
// MFMA GEMM (Linear semantics): out[m][n] = (sum_k A[m][k]*W[n][k] + bias[n])
//                                           * (n < qcols ? qscale : 1)
// 128x128 tile, 256 thr, templated BK (round-7 proven structure generalized):
//   BKT=64  -> 32 KB LDS, 3 blocks/CU (VGPR-capped)  — QKV (grid 1536)
//   BKT=128 -> 64 KB LDS, 2 blocks/CU — FREE for out-proj (grid 512 = 2/CU
//              grid-capped anyway); halves sync events 16 -> 8.
// Staging: mod-CPR chunk rotation (CPR = BKT/8 16B-chunks per row); read
// slot (ks*4+quad+ra)&(CPR-1) -> 8 distinct 16B bank columns (same proven
// pattern as BK=32/64). K-accumulation order bitwise identical across BKT.
// R6->R7 (+11 µs) proved sync-event count is the binding GEMM stall; R8
// (ring-3, same barrier count) tied R7, confirming events not drain latency.
// XCD-bijective block swizzle kept.
// ---------------------------------------------------------------------------
template<bool BF16OUT, int BKT>
__global__ __launch_bounds__(256) void gemm_mfma_bt(
    const unsigned short* __restrict__ A,
    const unsigned short* __restrict__ W,
    const float* __restrict__ bias,
    void* __restrict__ outv,
    int M, int N, int K, int qcols, float qscale)
{
    constexpr int CPR    = BKT / 8;      // 16B chunks per row
    constexpr int RPR    = 256 / CPR;    // rows staged per 4KB round
    constexpr int NROUND = 128 / RPR;    // rounds per matrix per K-tile

    __shared__ __align__(16) unsigned short As[128 * BKT];
    __shared__ __align__(16) unsigned short Bs[128 * BKT];

    // XCD-bijective swizzle (requires nwg % 8 == 0; both our grids qualify)
    int bxs = blockIdx.x, bys = blockIdx.y;
    {
        const int nx  = gridDim.x;
        const int nwg = nx * gridDim.y;
        if ((nwg & 7) == 0) {
            const int orig = bys * nx + bxs;
            const int nf   = (orig & 7) * (nwg >> 3) + (orig >> 3);
            bxs = nf % nx;
            bys = nf / nx;
        }
    }

    const int tid  = threadIdx.x;
    const int bm   = bys * 128;
    const int bn   = bxs * 128;
    const int wave = tid >> 6;
    const int lane = tid & 63;
    const int m16  = lane & 15;
    const int quad = lane >> 4;
    const int wm   = (wave & 1) * 64;
    const int wn   = (wave >> 1) * 64;

    // staging: thread covers rows r0 + k*RPR (RPR % CPR-period aligned:
    // RPR % CPR == 0 for BKT>=64... actually RPR*? — g0 shared because
    // RPR % CPR == 0 (64: 32%8, 128: 16%16) -> same chunk for all rounds.
    const int r0 = tid / CPR;
    const int s0 = tid % CPR;
    const int g0 = (s0 - r0) & (CPR - 1);

    f32x4 acc[4][4];
    f32x4 zero = {0.f, 0.f, 0.f, 0.f};
#pragma unroll
    for (int i = 0; i < 4; ++i)
#pragma unroll
        for (int j = 0; j < 4; ++j) acc[i][j] = zero;

    for (int kt = 0; kt < K; kt += BKT) {
        BARRIER();                       // WAR: prev step's frag reads all done
#pragma unroll
        for (int c = 0; c < NROUND; ++c) {
            const int row = c * RPR + r0;
            load_lds16(A + (size_t)(bm + row) * K + kt + g0 * 8,
                       As + c * 2048 + tid * 8);
            load_lds16(W + (size_t)(bn + row) * K + kt + g0 * 8,
                       Bs + c * 2048 + tid * 8);
        }
        WAIT_VM(0);
        BARRIER();                       // all waves' stages visible

#pragma unroll
        for (int ks = 0; ks < BKT / 32; ++ks) {
            bhalf8 af[4], bf[4];
#pragma unroll
            for (int i = 0; i < 4; ++i) {
                int ra = wm + i * 16 + m16;
                int sa = (ks * 4 + quad + ra) & (CPR - 1);
                af[i] = *(const bhalf8*)&As[ra * BKT + sa * 8];
            }
#pragma unroll
            for (int j = 0; j < 4; ++j) {
                int rb = wn + j * 16 + m16;
                int sb = (ks * 4 + quad + rb) & (CPR - 1);
                bf[j] = *(const bhalf8*)&Bs[rb * BKT + sb * 8];
            }
#pragma unroll
            for (int i = 0; i < 4; ++i)
#pragma unroll
                for (int j = 0; j < 4; ++j)
                    acc[i][j] = MFMA16(af[i], bf[j], acc[i][j]);
        }
    }

    float bj[4], scj[4];
#pragma unroll
    for (int j = 0; j < 4; ++j) {
        int col = bn + wn + j * 16 + m16;
        bj[j]  = bias[col];
        scj[j] = (col < qcols) ? qscale : 1.0f;
    }

#pragma unroll
    for (int i = 0; i < 4; ++i) {
#pragma unroll
        for (int r = 0; r < 4; ++r) {
            size_t row = (size_t)(bm + wm + i * 16 + quad * 4 + r);
            if (BF16OUT) {
                unsigned short* dst = (unsigned short*)outv + row * N + bn + wn;
#pragma unroll
                for (int j = 0; j < 4; ++j)
                    dst[j * 16 + m16] = f2bf((acc[i][j][r] + bj[j]) * scj[j]);
            } else {
                float* dst = (float*)outv + row * N + bn + wn;
#pragma unroll
                for (int j = 0; j < 4; ++j)
                    dst[j * 16 + m16] = (acc[i][j][r] + bj[j]) * scj[j];
            }
        }
    }
}

// ---------------------------------------------------------------------------
// MFMA flash attention — ROUND-2/6 KERNEL, FROZEN (measured 87-89 µs, best
// of all rounds). 128 q-rows/block, 4 waves x 32 rows, 3-barrier
// counted-vmcnt pipeline, XCD-bijective swizzle (FETCH 139->26 MB).
// Rounds 3/4/5 established: 1-barrier dbuf (-), 8-wave blocks (spill, -),
// QBLK=64 high-occupancy (-). Grid-capped at 16 waves/CU; local optimum.
// ---------------------------------------------------------------------------
__global__ __launch_bounds__(256, 4) void attn_mfma_kernel(
    const unsigned short* __restrict__ qkv, unsigned short* __restrict__ ctx)
{
    // bijective XCD swizzle: 1024 blocks = 8 * 128 exactly
    const int orig = blockIdx.x + (blockIdx.y << 4) + (blockIdx.z << 8);
    const int flat = ((orig & 7) << 7) | (orig >> 3);
    const int qt = flat & 15;            // 0..15 (128-row q tiles)
    const int h  = (flat >> 4) & 15;     // 0..15
    const int b  = flat >> 8;            // 0..3

    const int tid  = threadIdx.x;
    const int wave = tid >> 6;
    const int lane = tid & 63;
    const int m16  = lane & 15;
    const int quad = lane >> 4;

    __shared__ __align__(16) unsigned short K_lds[64 * 64];        // 8 KB
    __shared__ __align__(16) unsigned short Vt_lds[64 * 72];       // 9 KB
    __shared__ __align__(16) unsigned short QP_lds[4 * 32 * 72];   // 18 KB: Q stage, then P

    const int srow  = tid >> 3;          // 0..31 per 32-row staging chunk
    const int sslot = tid & 7;
    const int gk    = (sslot - srow) & 7;   // same rotation for both 32-row halves

    // V staging assignment: thread u handles key pair (k0, k0+16) -> storage
    // idx0, idx0+1 (adjacent); 8 d-rows starting vd0.
    const int u    = tid & 31;
    const int k0   = (u & 15) | ((u & 16) << 1);
    const int idx0 = (u & 15) * 4 + ((u >> 4) << 1);
    const int vd0  = (tid >> 5) * 8;

    const unsigned short* kPtr =
        qkv + ((size_t)b * SLEN) * QKV_N + D_MODEL + h * HDIM
            + (size_t)srow * QKV_N + gk * 8;
    const unsigned short* vPtr0 =
        qkv + ((size_t)b * SLEN) * QKV_N + 2 * D_MODEL + h * HDIM
            + (size_t)k0 * QKV_N + vd0;
    const unsigned short* vPtr1 = vPtr0 + (size_t)16 * QKV_N;

    uint4 va_A, vb_A, va_B, vb_B;

#define ISSUE_K(T) do {                                                      \
        const unsigned short* kb_ = kPtr + (size_t)(T) * 64 * QKV_N;         \
        load_lds16(kb_,                        K_lds + tid * 8);             \
        load_lds16(kb_ + (size_t)32 * QKV_N,   K_lds + 2048 + tid * 8);      \
    } while (0)

#define ISSUE_V(T, VA, VB) do {                                              \
        VA = *(const uint4*)(vPtr0 + (size_t)(T) * 64 * QKV_N);              \
        VB = *(const uint4*)(vPtr1 + (size_t)(T) * 64 * QKV_N);              \
    } while (0)

#define WRITE_V(VA, VB) do {                                                                         \
        *(unsigned int*)&Vt_lds[(vd0 + 0) * 72 + idx0] = __builtin_amdgcn_perm(VB.x, VA.x, 0x05040100u); \
        *(unsigned int*)&Vt_lds[(vd0 + 1) * 72 + idx0] = __builtin_amdgcn_perm(VB.x, VA.x, 0x07060302u); \
        *(unsigned int*)&Vt_lds[(vd0 + 2) * 72 + idx0] = __builtin_amdgcn_perm(VB.y, VA.y, 0x05040100u); \
        *(unsigned int*)&Vt_lds[(vd0 + 3) * 72 + idx0] = __builtin_amdgcn_perm(VB.y, VA.y, 0x07060302u); \
        *(unsigned int*)&Vt_lds[(vd0 + 4) * 72 + idx0] = __builtin_amdgcn_perm(VB.z, VA.z, 0x05040100u); \
        *(unsigned int*)&Vt_lds[(vd0 + 5) * 72 + idx0] = __builtin_amdgcn_perm(VB.z, VA.z, 0x07060302u); \
        *(unsigned int*)&Vt_lds[(vd0 + 6) * 72 + idx0] = __builtin_amdgcn_perm(VB.w, VA.w, 0x05040100u); \
        *(unsigned int*)&Vt_lds[(vd0 + 7) * 72 + idx0] = __builtin_amdgcn_perm(VB.w, VA.w, 0x07060302u); \
    } while (0)

    // ---- prologue: stage Q (4 ops), K(0) (2 ops), V(0) regs (2 ops) ----
    {
        const unsigned short* qbase =
            qkv + (size_t)(b * SLEN + qt * 128) * QKV_N + h * HDIM;
#pragma unroll
        for (int c = 0; c < 4; ++c) {
            int r = c * 32 + srow;
            int g = (sslot - r) & 7;
            load_lds16(qbase + (size_t)r * QKV_N + g * 8,
                       QP_lds + c * 2048 + tid * 8);
        }
    }
    ISSUE_K(0);
    ISSUE_V(0, va_A, vb_A);
    WAIT_VM(2);            // Q(4)+K0(2) landed; V0 regs still in flight
    BARRIER();

    // ---- hoist Q frags (loop-invariant); QP region becomes P afterwards ----
    bhalf8 qf[2][2];
#pragma unroll
    for (int qi = 0; qi < 2; ++qi) {
        int rq = wave * 32 + qi * 16 + m16;
#pragma unroll
        for (int ks = 0; ks < 2; ++ks) {
            int slot = (ks * 4 + quad + rq) & 7;
            qf[qi][ks] = *(const bhalf8*)&QP_lds[rq * 64 + slot * 8];
        }
    }

    WAIT_VM(0);                 // V(0) regs landed
    WRITE_V(va_A, vb_A);        // V(0) -> Vt_lds
    ISSUE_V(1, va_B, vb_B);     // V(1) regs in flight (2 ops)
    WAIT_LGKM0();
    BARRIER();
    // loop-entry invariant at t: K_lds=K(t) ready, Vt_lds=V(t) ready,
    // V(t+1) regs in flight, K(t+1) not yet issued.

    f32x4 zero = {0.f, 0.f, 0.f, 0.f};
    f32x4 oacc[2][4], oacc_l[2];
#pragma unroll
    for (int qi = 0; qi < 2; ++qi) {
        oacc_l[qi] = zero;
#pragma unroll
        for (int dt = 0; dt < 4; ++dt) oacc[qi][dt] = zero;
    }

    bhalf8 ones;
#pragma unroll
    for (int i = 0; i < 8; ++i) ones[i] = (short)0x3F80;   // bf16 1.0

    unsigned short* P = &QP_lds[wave * (32 * 72)];
    f32x4 sacc[2][4];

#define QKT_PHASE() do {                                                     \
        _Pragma("unroll")                                                    \
        for (int qi = 0; qi < 2; ++qi)                                       \
            _Pragma("unroll")                                                \
            for (int nt = 0; nt < 4; ++nt) sacc[qi][nt] = zero;              \
        __builtin_amdgcn_s_setprio(1);                                       \
        _Pragma("unroll")                                                    \
        for (int ks = 0; ks < 2; ++ks) {                                     \
            _Pragma("unroll")                                                \
            for (int nt = 0; nt < 4; ++nt) {                                 \
                int rk = nt * 16 + m16;                                      \
                int slot = (ks * 4 + quad + rk) & 7;                         \
                bhalf8 kf = *(const bhalf8*)&K_lds[rk * 64 + slot * 8];      \
                sacc[0][nt] = MFMA16(qf[0][ks], kf, sacc[0][nt]);            \
                sacc[1][nt] = MFMA16(qf[1][ks], kf, sacc[1][nt]);            \
            }                                                                \
        }                                                                    \
        __builtin_amdgcn_s_setprio(0);                                       \
    } while (0)

#define SOFTMAX_PHASE() do {                                                 \
        _Pragma("unroll")                                                    \
        for (int qi = 0; qi < 2; ++qi) {                                     \
            _Pragma("unroll")                                                \
            for (int r = 0; r < 4; ++r) {                                    \
                float p0 = EXP2(sacc[qi][0][r]);                             \
                float p1 = EXP2(sacc[qi][1][r]);                             \
                float p2 = EXP2(sacc[qi][2][r]);                             \
                float p3 = EXP2(sacc[qi][3][r]);                             \
                uint2 w;                                                     \
                w.x = pack_hi16(p0, p1);                                     \
                w.y = pack_hi16(p2, p3);                                     \
                *(uint2*)&P[(qi * 16 + quad * 4 + r) * 72 + m16 * 4] = w;    \
            }                                                                \
        }                                                                    \
        WAIT_LGKM0();                                                        \
        __builtin_amdgcn_sched_barrier(0);                                   \
    } while (0)

#define PV_PHASE() do {                                                      \
        __builtin_amdgcn_s_setprio(1);                                       \
        _Pragma("unroll")                                                    \
        for (int ks = 0; ks < 2; ++ks) {                                     \
            bhalf8 pf0 = *(const bhalf8*)&P[(m16)      * 72 + ks * 32 + quad * 8]; \
            bhalf8 pf1 = *(const bhalf8*)&P[(16 + m16) * 72 + ks * 32 + quad * 8]; \
            oacc_l[0] = MFMA16(pf0, ones, oacc_l[0]);                        \
            oacc_l[1] = MFMA16(pf1, ones, oacc_l[1]);                        \
            _Pragma("unroll")                                                \
            for (int dt = 0; dt < 4; ++dt) {                                 \
                bhalf8 vf = *(const bhalf8*)&Vt_lds[(dt * 16 + m16) * 72 + ks * 32 + quad * 8]; \
                oacc[0][dt] = MFMA16(pf0, vf, oacc[0][dt]);                  \
                oacc[1][dt] = MFMA16(pf1, vf, oacc[1][dt]);                  \
            }                                                                \
        }                                                                    \
        __builtin_amdgcn_s_setprio(0);                                       \
    } while (0)

// full-pipeline tile: issue K(T+1), write V(T+1), issue V(T+2)
#define TILE_FULL(T, VWA, VWB, VLA, VLB) do {                                \
        QKT_PHASE();                                                         \
        BARRIER();                    /* B1: all waves done reading K_lds */ \
        ISSUE_K((T) + 1);                                                    \
        SOFTMAX_PHASE();                                                     \
        PV_PHASE();                                                          \
        BARRIER();                    /* B2: all waves done reading Vt/P  */ \
        WAIT_VM(2);                   /* V(T+1) regs landed; K(T+1) fly  */  \
        WRITE_V(VWA, VWB);                                                   \
        ISSUE_V((T) + 2, VLA, VLB);                                          \
        WAIT_VM(2);                   /* K(T+1) landed; V(T+2) in flight */  \
        WAIT_LGKM0();                                                        \
        BARRIER();                    /* B3: K(T+1)/Vt(T+1) visible */       \
    } while (0)

    // main loop: tiles 0..29, x2 unroll for static V-reg set parity
    for (int t2 = 0; t2 < 30; t2 += 2) {
        TILE_FULL(t2,     va_B, vb_B, va_A, vb_A);
        TILE_FULL(t2 + 1, va_A, vb_A, va_B, vb_B);
    }

    // t = 30: issue K(31), write V(31) (setB), no V(32)
    QKT_PHASE();
    BARRIER();
    ISSUE_K(31);
    SOFTMAX_PHASE();
    PV_PHASE();
    BARRIER();
    WAIT_VM(2);                 // V(31) regs landed
    WRITE_V(va_B, vb_B);
    WAIT_VM(0);                 // K(31) landed
    WAIT_LGKM0();
    BARRIER();

    // t = 31: pure compute
    QKT_PHASE();
    SOFTMAX_PHASE();
    PV_PHASE();

#undef TILE_FULL
#undef PV_PHASE
#undef SOFTMAX_PHASE
#undef QKT_PHASE
#undef WRITE_V
#undef ISSUE_V
#undef ISSUE_K

    // ---- epilogue: l is per-lane in C-layout (same col value across cols) ----
#pragma unroll
    for (int qi = 0; qi < 2; ++qi) {
#pragma unroll
        for (int r = 0; r < 4; ++r) {
            float inv = 1.0f / oacc_l[qi][r];
            int row = b * SLEN + qt * 128 + wave * 32 + qi * 16 + quad * 4 + r;
            unsigned short* dst = ctx + (size_t)row * D_MODEL + h * HDIM;
#pragma unroll
            for (int dt = 0; dt < 4; ++dt)
                dst[dt * 16 + m16] = f2bf(oacc[qi][dt][r] * inv);
        }
    }
}

// ---------------------------------------------------------------------------
extern "C" void kernel_launch(void* const* d_in, const int* in_sizes, int n_in,
                              void* d_out, int out_size, void* d_ws, size_t ws_size,
                              hipStream_t stream)
{
    const float* x     = (const float*)d_in[0];   // [4,2048,1024]
    const float* qkv_w = (const float*)d_in[1];   // [3072,1024]
    const float* qkv_b = (const float*)d_in[2];   // [3072]
    const float* out_w = (const float*)d_in[3];   // [1024,1024]
    const float* out_b = (const float*)d_in[4];   // [1024]
    float* out = (float*)d_out;                   // [4,2048,1024]

    unsigned short* xbf  = (unsigned short*)d_ws;                 // [8192,1024]
    unsigned short* wqkv = xbf  + (size_t)MROWS * D_MODEL;        // [3072,1024]
    unsigned short* wout = wqkv + (size_t)QKV_N * D_MODEL;        // [1024,1024]
    unsigned short* qkv  = wout + (size_t)D_MODEL * D_MODEL;      // [8192,3072]
    unsigned short* ctx  = qkv  + (size_t)MROWS * QKV_N;          // [8192,1024]

    // 0) fused fp32 -> bf16 casts (one dispatch)
    {
        const int na = MROWS * D_MODEL;      // 8388608
        const int nb = QKV_N * D_MODEL;      // 3145728
        const int nc = D_MODEL * D_MODEL;    // 1048576
        const int total = na + nb + nc;      // 12582912, /1024 = 12288
        cast3_f32_bf16<<<total / 1024, 256, 0, stream>>>(
            x, xbf, na, qkv_w, wqkv, nb, out_w, wout, nc);
    }

    const float QSCALE = 0.125f * 1.44269504088896f;   // 1/sqrt(64) * log2(e)

    // 1) QKV projection (BK=64, round-7 proven); q columns pre-scaled for exp2
    {
        dim3 grid(QKV_N / 128, MROWS / 128);   // 24 x 64 = 1536 blocks (%8==0)
        gemm_mfma_bt<true, 64><<<grid, 256, 0, stream>>>(
            xbf, wqkv, qkv_b, qkv, MROWS, QKV_N, D_MODEL, D_MODEL, QSCALE);
    }

    // 2) round-2 pipelined MFMA flash attention -> bf16 ctx (frozen)
    {
        dim3 grid(SLEN / 128, NHEADS, BATCH);
        attn_mfma_kernel<<<grid, 256, 0, stream>>>(qkv, ctx);
    }

    // 3) output projection (BK=128: grid-capped at 2 blocks/CU so 64 KB LDS
    //    is free; sync events halve 16 -> 8) -> fp32 d_out
    {
        dim3 grid(D_MODEL / 128, MROWS / 128); // 8 x 64 = 512 blocks (%8==0)
        gemm_mfma_bt<false, 128><<<grid, 256, 0, stream>>>(
            ctx, wout, out_b, out, MROWS, D_MODEL, D_MODEL, 0, 1.0f);
    }
}